// Round 1
// baseline (2095.905 us; speedup 1.0000x reference)
//
#include <hip/hip_runtime.h>
#include <hip/hip_bf16.h>
#include <cstddef>
#include <cstdint>

#define NNODES 50000
#define NR 3
#define NE 800000
#define HIDF 128
#define OUTF 64
#define NEG_SLOPE 0.01f
#define SCAN_T 1024
#define NCHUNK ((NNODES + SCAN_T - 1) / SCAN_T)   // 49

// ---------------------------------------------------------------------------
// 1) Degree histograms (int atomics)
// ---------------------------------------------------------------------------
__global__ __launch_bounds__(256) void k_degrees(const int* __restrict__ esrc,
                                                 const int* __restrict__ edst,
                                                 int* __restrict__ deg_out,
                                                 int* __restrict__ deg_in) {
    int idx = blockIdx.x * blockDim.x + threadIdx.x;
    if (idx >= NR * NE) return;
    int r = idx / NE;
    int s = esrc[idx];
    int d = edst[idx];
    atomicAdd(&deg_out[r * NNODES + s], 1);
    atomicAdd(&deg_in[r * NNODES + d], 1);
}

// ---------------------------------------------------------------------------
// 2) Norms: rsqrt(max(deg,1))
// ---------------------------------------------------------------------------
__global__ __launch_bounds__(256) void k_norms(const int* __restrict__ deg_out,
                                               const int* __restrict__ deg_in,
                                               float* __restrict__ out_norm,
                                               float* __restrict__ in_norm) {
    int idx = blockIdx.x * blockDim.x + threadIdx.x;
    if (idx >= NR * NNODES) return;
    int dout = deg_out[idx];
    int din  = deg_in[idx];
    out_norm[idx] = rsqrtf((float)(dout > 1 ? dout : 1));
    in_norm[idx]  = rsqrtf((float)(din  > 1 ? din  : 1));
}

// ---------------------------------------------------------------------------
// 3) CSR build: per-chunk inclusive scan -> chunk sums -> offsets -> add
// ---------------------------------------------------------------------------
__global__ __launch_bounds__(SCAN_T) void k_scan1(const int* __restrict__ deg_in,
                                                  int* __restrict__ row_ptr,
                                                  int* __restrict__ csums) {
    __shared__ int buf[SCAN_T];
    int r = blockIdx.x / NCHUNK;
    int c = blockIdx.x % NCHUNK;
    int tid = threadIdx.x;
    int i = c * SCAN_T + tid;
    int v = (i < NNODES) ? deg_in[r * NNODES + i] : 0;
    buf[tid] = v;
    __syncthreads();
    for (int off = 1; off < SCAN_T; off <<= 1) {
        int t = (tid >= off) ? buf[tid - off] : 0;
        __syncthreads();
        buf[tid] += t;
        __syncthreads();
    }
    if (i < NNODES) row_ptr[r * (NNODES + 1) + i + 1] = buf[tid];
    if (tid == SCAN_T - 1) csums[r * NCHUNK + c] = buf[SCAN_T - 1];
}

__global__ void k_scan2(const int* __restrict__ csums, int* __restrict__ coffs) {
    int r = threadIdx.x;
    if (r >= NR) return;
    int run = 0;
    for (int c = 0; c < NCHUNK; ++c) {
        coffs[r * NCHUNK + c] = run;
        run += csums[r * NCHUNK + c];
    }
}

__global__ __launch_bounds__(SCAN_T) void k_scan3(int* __restrict__ row_ptr,
                                                  const int* __restrict__ coffs) {
    int r = blockIdx.x / NCHUNK;
    int c = blockIdx.x % NCHUNK;
    int tid = threadIdx.x;
    int i = c * SCAN_T + tid;
    int off = coffs[r * NCHUNK + c];
    if (i < NNODES) row_ptr[r * (NNODES + 1) + i + 1] += off;
    if (tid == 0 && c == 0) row_ptr[r * (NNODES + 1)] = 0;
}

__global__ __launch_bounds__(256) void k_fill_csr(const int* __restrict__ esrc,
                                                  const int* __restrict__ edst,
                                                  const int* __restrict__ row_ptr,
                                                  int* __restrict__ cursor,
                                                  int* __restrict__ csr_src) {
    int idx = blockIdx.x * blockDim.x + threadIdx.x;
    if (idx >= NR * NE) return;
    int r = idx / NE;
    int s = esrc[idx];
    int d = edst[idx];
    int pos = atomicAdd(&cursor[r * NNODES + d], 1);
    csr_src[(size_t)r * NE + row_ptr[r * (NNODES + 1) + d] + pos] = s;
}

// ---------------------------------------------------------------------------
// 4) Aggregation: one wave per (relation, dst node); 128 feats = 2 per lane
//    agg[r][n] = in_norm[r][n] * sum_{e in CSR row n} out_norm[r][src] * h[src]
// ---------------------------------------------------------------------------
__global__ __launch_bounds__(256) void k_aggregate(const float* __restrict__ hin,
                                                   const float* __restrict__ out_norm,
                                                   const float* __restrict__ in_norm,
                                                   const int* __restrict__ row_ptr,
                                                   const int* __restrict__ csr_src,
                                                   float* __restrict__ agg) {
    int wave = blockIdx.x * 4 + (threadIdx.x >> 6);
    if (wave >= NR * NNODES) return;
    int r = wave / NNODES;
    int n = wave - r * NNODES;
    int lane = threadIdx.x & 63;
    int start = row_ptr[r * (NNODES + 1) + n];
    int end   = row_ptr[r * (NNODES + 1) + n + 1];
    const int* cs = csr_src + (size_t)r * NE;
    const float* onorm = out_norm + r * NNODES;
    float acc0 = 0.f, acc1 = 0.f;
    for (int i = start; i < end; ++i) {
        int s = cs[i];
        float w = onorm[s];
        const float* hp = hin + (size_t)s * HIDF;
        acc0 = fmaf(w, hp[lane], acc0);
        acc1 = fmaf(w, hp[lane + 64], acc1);
    }
    float wn = in_norm[r * NNODES + n];
    float* ap = agg + (size_t)wave * HIDF;
    ap[lane]      = acc0 * wn;
    ap[lane + 64] = acc1 * wn;
}

// ---------------------------------------------------------------------------
// 5) Per-layer matmul: h_out[N,128] = act( (1/3) * sum_r agg_r @ W_r + bmean )
//    Tile: 64 rows x 128 cols per block (256 thr), K = 3*128 chunked by 16.
// ---------------------------------------------------------------------------
__global__ __launch_bounds__(256) void k_conv_mm(const float* __restrict__ agg,
                                                 const float* __restrict__ W,
                                                 const float* __restrict__ bias,
                                                 float* __restrict__ hout,
                                                 int act) {
    __shared__ float At[16][68];    // [k][m], padded (272B row = 16B aligned)
    __shared__ float Bt[16][128];   // [k][n]
    int tid = threadIdx.x;
    int tx = tid & 15;              // 16 col groups * 8 cols
    int ty = tid >> 4;              // 16 row groups * 4 rows
    int block_row = blockIdx.x * 64;

    int arow = tid >> 2;            // 0..63
    int akq  = (tid & 3) * 4;       // 0,4,8,12
    int grow = block_row + arow;
    int kb   = tid >> 4;            // 0..15
    int bcol = (tid & 15) * 8;

    float acc[4][8];
#pragma unroll
    for (int i = 0; i < 4; ++i)
#pragma unroll
        for (int j = 0; j < 8; ++j) acc[i][j] = 0.f;

    for (int c = 0; c < NR * (HIDF / 16); ++c) {
        int r  = c >> 3;            // 8 chunks per relation
        int k0 = (c & 7) * 16;
        float4 av = make_float4(0.f, 0.f, 0.f, 0.f);
        if (grow < NNODES)
            av = *(const float4*)(agg + ((size_t)r * NNODES + grow) * HIDF + k0 + akq);
        At[akq + 0][arow] = av.x;
        At[akq + 1][arow] = av.y;
        At[akq + 2][arow] = av.z;
        At[akq + 3][arow] = av.w;
        const float* wp = W + ((size_t)r * HIDF + (k0 + kb)) * HIDF + bcol;
        float4 b0v = *(const float4*)(wp);
        float4 b1v = *(const float4*)(wp + 4);
        *(float4*)&Bt[kb][bcol]     = b0v;
        *(float4*)&Bt[kb][bcol + 4] = b1v;
        __syncthreads();
#pragma unroll
        for (int kk = 0; kk < 16; ++kk) {
            float4 a  = *(const float4*)&At[kk][ty * 4];
            float4 b0 = *(const float4*)&Bt[kk][tx * 8];
            float4 b1 = *(const float4*)&Bt[kk][tx * 8 + 4];
            float avv[4] = {a.x, a.y, a.z, a.w};
            float bvv[8] = {b0.x, b0.y, b0.z, b0.w, b1.x, b1.y, b1.z, b1.w};
#pragma unroll
            for (int i = 0; i < 4; ++i)
#pragma unroll
                for (int j = 0; j < 8; ++j)
                    acc[i][j] = fmaf(avv[i], bvv[j], acc[i][j]);
        }
        __syncthreads();
    }

    const float inv3 = 1.f / 3.f;
#pragma unroll
    for (int j = 0; j < 8; ++j) {
        int col = tx * 8 + j;
        float bm = (bias[col] + bias[HIDF + col] + bias[2 * HIDF + col]) * inv3;
#pragma unroll
        for (int i = 0; i < 4; ++i) {
            int row = block_row + ty * 4 + i;
            if (row < NNODES) {
                float v = acc[i][j] * inv3 + bm;
                if (act) v = (v > 0.f) ? v : NEG_SLOPE * v;
                hout[(size_t)row * HIDF + col] = v;
            }
        }
    }
}

// ---------------------------------------------------------------------------
// 6) Final linear: out[N,64] = h @ Wout + bout
// ---------------------------------------------------------------------------
__global__ __launch_bounds__(256) void k_final(const float* __restrict__ h,
                                               const float* __restrict__ Wout,
                                               const float* __restrict__ bout,
                                               float* __restrict__ out) {
    int tid = threadIdx.x;
    int col = tid & 63;
    int row = blockIdx.x * 4 + (tid >> 6);
    if (row >= NNODES) return;
    const float* hp = h + (size_t)row * HIDF;
    float acc = bout[col];
#pragma unroll 8
    for (int k = 0; k < HIDF; ++k)
        acc = fmaf(hp[k], Wout[k * OUTF + col], acc);
    out[(size_t)row * OUTF + col] = acc;
}

// ---------------------------------------------------------------------------
// Host launcher
// ---------------------------------------------------------------------------
extern "C" void kernel_launch(void* const* d_in, const int* in_sizes, int n_in,
                              void* d_out, int out_size, void* d_ws, size_t ws_size,
                              hipStream_t stream) {
    const float* x    = (const float*)d_in[0];
    const int*   esrc = (const int*)d_in[1];
    const int*   edst = (const int*)d_in[2];
    const float* W0   = (const float*)d_in[3];
    const float* b0   = (const float*)d_in[4];
    const float* Wl   = (const float*)d_in[5];
    const float* bl   = (const float*)d_in[6];
    const float* Wout = (const float*)d_in[7];
    const float* bout = (const float*)d_in[8];
    float* out = (float*)d_out;

    char* ws = (char*)d_ws;
    size_t off = 0;
    auto carve = [&](size_t bytes) {
        size_t p = off;
        off += (bytes + 255) & ~(size_t)255;
        return p;
    };
    const size_t SZ_RN_I = (size_t)NR * NNODES * 4;
    // NOTE: deg_out, deg_in, cursor must be contiguous (single memset)
    size_t o_deg_out = carve(SZ_RN_I);
    size_t o_deg_in  = carve(SZ_RN_I);
    size_t o_cursor  = carve(SZ_RN_I);
    size_t zero_span = off;                        // bytes to zero
    size_t o_out_nrm = carve(SZ_RN_I);
    size_t o_in_nrm  = carve(SZ_RN_I);
    size_t o_row_ptr = carve((size_t)NR * (NNODES + 1) * 4);
    size_t o_csums   = carve((size_t)NR * NCHUNK * 4);
    size_t o_coffs   = carve((size_t)NR * NCHUNK * 4);
    size_t o_csr     = carve((size_t)NR * NE * 4);
    size_t o_agg     = carve((size_t)NR * NNODES * HIDF * 4);
    size_t o_h       = carve((size_t)NNODES * HIDF * 4);
    (void)ws_size;

    int*   deg_out  = (int*)(ws + o_deg_out);
    int*   deg_in   = (int*)(ws + o_deg_in);
    int*   cursor   = (int*)(ws + o_cursor);
    float* out_norm = (float*)(ws + o_out_nrm);
    float* in_norm  = (float*)(ws + o_in_nrm);
    int*   row_ptr  = (int*)(ws + o_row_ptr);
    int*   csums    = (int*)(ws + o_csums);
    int*   coffs    = (int*)(ws + o_coffs);
    int*   csr_src  = (int*)(ws + o_csr);
    float* agg      = (float*)(ws + o_agg);
    float* h        = (float*)(ws + o_h);

    hipMemsetAsync(ws, 0, zero_span, stream);

    int nEdgeBlocks = (NR * NE + 255) / 256;
    k_degrees<<<nEdgeBlocks, 256, 0, stream>>>(esrc, edst, deg_out, deg_in);
    k_norms<<<(NR * NNODES + 255) / 256, 256, 0, stream>>>(deg_out, deg_in, out_norm, in_norm);
    k_scan1<<<NR * NCHUNK, SCAN_T, 0, stream>>>(deg_in, row_ptr, csums);
    k_scan2<<<1, 64, 0, stream>>>(csums, coffs);
    k_scan3<<<NR * NCHUNK, SCAN_T, 0, stream>>>(row_ptr, coffs);
    k_fill_csr<<<nEdgeBlocks, 256, 0, stream>>>(esrc, edst, row_ptr, cursor, csr_src);

    const int aggBlocks = (NR * NNODES + 3) / 4;        // 4 waves/block
    const int mmBlocks  = (NNODES + 63) / 64;

    const float* hin = x;
    for (int l = 0; l < 5; ++l) {
        k_aggregate<<<aggBlocks, 256, 0, stream>>>(hin, out_norm, in_norm, row_ptr, csr_src, agg);
        const float* Wp = (l == 0) ? W0 : Wl + (size_t)(l - 1) * NR * HIDF * HIDF;
        const float* bp = (l == 0) ? b0 : bl + (size_t)(l - 1) * NR * HIDF;
        k_conv_mm<<<mmBlocks, 256, 0, stream>>>(agg, Wp, bp, h, (l < 4) ? 1 : 0);
        hin = h;
    }
    k_final<<<(NNODES + 3) / 4, 256, 0, stream>>>(h, Wout, bout, out);
}

// Round 2
// 1528.567 us; speedup vs baseline: 1.3712x; 1.3712x over previous
//
#include <hip/hip_runtime.h>
#include <hip/hip_bf16.h>
#include <cstddef>
#include <cstdint>

#define NNODES 50000
#define NR 3
#define NE 800000
#define HIDF 128
#define OUTF 64
#define NEG_SLOPE 0.01f
#define SCAN_T 1024
#define NCHUNK ((NNODES + SCAN_T - 1) / SCAN_T)   // 49

// bf16 helpers: packed ushort2-in-uint, round-to-nearest-even on pack
__device__ __forceinline__ float bf_lo(uint v) { return __uint_as_float(v << 16); }
__device__ __forceinline__ float bf_hi(uint v) { return __uint_as_float(v & 0xffff0000u); }
__device__ __forceinline__ uint bf_rne(float f) {
    uint u = __float_as_uint(f);
    return (u + 0x7fffu + ((u >> 16) & 1u)) >> 16;
}
__device__ __forceinline__ uint bf_pack(float a, float b) {
    return bf_rne(a) | (bf_rne(b) << 16);
}

// ---------------------------------------------------------------------------
// 0) Cast x (fp32) -> packed bf16 rows
// ---------------------------------------------------------------------------
__global__ __launch_bounds__(256) void k_cast_x(const float* __restrict__ x,
                                                uint* __restrict__ xb) {
    int i = blockIdx.x * blockDim.x + threadIdx.x;   // uint index: N*64
    if (i >= NNODES * (HIDF / 2)) return;
    float2 v = *(const float2*)(x + (size_t)i * 2);
    xb[i] = bf_pack(v.x, v.y);
}

// ---------------------------------------------------------------------------
// 1) Degree histograms (int atomics)
// ---------------------------------------------------------------------------
__global__ __launch_bounds__(256) void k_degrees(const int* __restrict__ esrc,
                                                 const int* __restrict__ edst,
                                                 int* __restrict__ deg_out,
                                                 int* __restrict__ deg_in) {
    int idx = blockIdx.x * blockDim.x + threadIdx.x;
    if (idx >= NR * NE) return;
    int r = idx / NE;
    int s = esrc[idx];
    int d = edst[idx];
    atomicAdd(&deg_out[r * NNODES + s], 1);
    atomicAdd(&deg_in[r * NNODES + d], 1);
}

// ---------------------------------------------------------------------------
// 2) Norms: rsqrt(max(deg,1))
// ---------------------------------------------------------------------------
__global__ __launch_bounds__(256) void k_norms(const int* __restrict__ deg_out,
                                               const int* __restrict__ deg_in,
                                               float* __restrict__ out_norm,
                                               float* __restrict__ in_norm) {
    int idx = blockIdx.x * blockDim.x + threadIdx.x;
    if (idx >= NR * NNODES) return;
    int dout = deg_out[idx];
    int din  = deg_in[idx];
    out_norm[idx] = rsqrtf((float)(dout > 1 ? dout : 1));
    in_norm[idx]  = rsqrtf((float)(din  > 1 ? din  : 1));
}

// ---------------------------------------------------------------------------
// 3) CSR build: per-chunk inclusive scan -> chunk sums -> offsets -> add
// ---------------------------------------------------------------------------
__global__ __launch_bounds__(SCAN_T) void k_scan1(const int* __restrict__ deg_in,
                                                  int* __restrict__ row_ptr,
                                                  int* __restrict__ csums) {
    __shared__ int buf[SCAN_T];
    int r = blockIdx.x / NCHUNK;
    int c = blockIdx.x % NCHUNK;
    int tid = threadIdx.x;
    int i = c * SCAN_T + tid;
    int v = (i < NNODES) ? deg_in[r * NNODES + i] : 0;
    buf[tid] = v;
    __syncthreads();
    for (int off = 1; off < SCAN_T; off <<= 1) {
        int t = (tid >= off) ? buf[tid - off] : 0;
        __syncthreads();
        buf[tid] += t;
        __syncthreads();
    }
    if (i < NNODES) row_ptr[r * (NNODES + 1) + i + 1] = buf[tid];
    if (tid == SCAN_T - 1) csums[r * NCHUNK + c] = buf[SCAN_T - 1];
}

__global__ void k_scan2(const int* __restrict__ csums, int* __restrict__ coffs) {
    int r = threadIdx.x;
    if (r >= NR) return;
    int run = 0;
    for (int c = 0; c < NCHUNK; ++c) {
        coffs[r * NCHUNK + c] = run;
        run += csums[r * NCHUNK + c];
    }
}

__global__ __launch_bounds__(SCAN_T) void k_scan3(int* __restrict__ row_ptr,
                                                  const int* __restrict__ coffs) {
    int r = blockIdx.x / NCHUNK;
    int c = blockIdx.x % NCHUNK;
    int tid = threadIdx.x;
    int i = c * SCAN_T + tid;
    int off = coffs[r * NCHUNK + c];
    if (i < NNODES) row_ptr[r * (NNODES + 1) + i + 1] += off;
    if (tid == 0 && c == 0) row_ptr[r * (NNODES + 1)] = 0;
}

__global__ __launch_bounds__(256) void k_fill_csr(const int* __restrict__ esrc,
                                                  const int* __restrict__ edst,
                                                  const int* __restrict__ row_ptr,
                                                  int* __restrict__ cursor,
                                                  int* __restrict__ csr_src) {
    int idx = blockIdx.x * blockDim.x + threadIdx.x;
    if (idx >= NR * NE) return;
    int r = idx / NE;
    int s = esrc[idx];
    int d = edst[idx];
    int pos = atomicAdd(&cursor[r * NNODES + d], 1);
    csr_src[(size_t)r * NE + row_ptr[r * (NNODES + 1) + d] + pos] = s;
}

// ---------------------------------------------------------------------------
// 4) Aggregation (bf16 gather, fp32 accumulate, 4-edge unroll for MLP)
//    one wave per (relation, dst node); lane holds feats {2*lane, 2*lane+1}
// ---------------------------------------------------------------------------
__global__ __launch_bounds__(256) void k_aggregate(const uint* __restrict__ hin,
                                                   const float* __restrict__ out_norm,
                                                   const float* __restrict__ in_norm,
                                                   const int* __restrict__ row_ptr,
                                                   const int* __restrict__ csr_src,
                                                   float* __restrict__ agg) {
    int wave = blockIdx.x * 4 + (threadIdx.x >> 6);
    if (wave >= NR * NNODES) return;
    int r = wave / NNODES;
    int n = wave - r * NNODES;
    int lane = threadIdx.x & 63;
    int start = row_ptr[r * (NNODES + 1) + n];
    int end   = row_ptr[r * (NNODES + 1) + n + 1];
    const int* cs = csr_src + (size_t)r * NE;
    const float* onorm = out_norm + r * NNODES;
    float acc0 = 0.f, acc1 = 0.f;
    int i = start;
    for (; i + 4 <= end; i += 4) {
        int s0 = cs[i], s1 = cs[i + 1], s2 = cs[i + 2], s3 = cs[i + 3];
        float w0 = onorm[s0], w1 = onorm[s1], w2 = onorm[s2], w3 = onorm[s3];
        uint v0 = hin[(size_t)s0 * (HIDF / 2) + lane];
        uint v1 = hin[(size_t)s1 * (HIDF / 2) + lane];
        uint v2 = hin[(size_t)s2 * (HIDF / 2) + lane];
        uint v3 = hin[(size_t)s3 * (HIDF / 2) + lane];
        acc0 = fmaf(w0, bf_lo(v0), acc0); acc1 = fmaf(w0, bf_hi(v0), acc1);
        acc0 = fmaf(w1, bf_lo(v1), acc0); acc1 = fmaf(w1, bf_hi(v1), acc1);
        acc0 = fmaf(w2, bf_lo(v2), acc0); acc1 = fmaf(w2, bf_hi(v2), acc1);
        acc0 = fmaf(w3, bf_lo(v3), acc0); acc1 = fmaf(w3, bf_hi(v3), acc1);
    }
    for (; i < end; ++i) {
        int s = cs[i];
        float w = onorm[s];
        uint v = hin[(size_t)s * (HIDF / 2) + lane];
        acc0 = fmaf(w, bf_lo(v), acc0);
        acc1 = fmaf(w, bf_hi(v), acc1);
    }
    float wn = in_norm[r * NNODES + n];
    float2 st = make_float2(acc0 * wn, acc1 * wn);
    *(float2*)(agg + (size_t)wave * HIDF + 2 * lane) = st;
}

// ---------------------------------------------------------------------------
// 5) Per-layer matmul (fp32): h_out = act( (1/3) * sum_r agg_r @ W_r + bmean )
//    64 rows x 128 cols per block (256 thr), K = 3*128 chunked by 16.
//    Epilogue writes h as packed bf16 (RNE).
// ---------------------------------------------------------------------------
__global__ __launch_bounds__(256) void k_conv_mm(const float* __restrict__ agg,
                                                 const float* __restrict__ W,
                                                 const float* __restrict__ bias,
                                                 uint* __restrict__ hout,
                                                 int act) {
    __shared__ float At[16][68];
    __shared__ float Bt[16][128];
    int tid = threadIdx.x;
    int tx = tid & 15;
    int ty = tid >> 4;
    int block_row = blockIdx.x * 64;

    int arow = tid >> 2;
    int akq  = (tid & 3) * 4;
    int grow = block_row + arow;
    int kb   = tid >> 4;
    int bcol = (tid & 15) * 8;

    float acc[4][8];
#pragma unroll
    for (int i = 0; i < 4; ++i)
#pragma unroll
        for (int j = 0; j < 8; ++j) acc[i][j] = 0.f;

    for (int c = 0; c < NR * (HIDF / 16); ++c) {
        int r  = c >> 3;
        int k0 = (c & 7) * 16;
        float4 av = make_float4(0.f, 0.f, 0.f, 0.f);
        if (grow < NNODES)
            av = *(const float4*)(agg + ((size_t)r * NNODES + grow) * HIDF + k0 + akq);
        At[akq + 0][arow] = av.x;
        At[akq + 1][arow] = av.y;
        At[akq + 2][arow] = av.z;
        At[akq + 3][arow] = av.w;
        const float* wp = W + ((size_t)r * HIDF + (k0 + kb)) * HIDF + bcol;
        float4 b0v = *(const float4*)(wp);
        float4 b1v = *(const float4*)(wp + 4);
        *(float4*)&Bt[kb][bcol]     = b0v;
        *(float4*)&Bt[kb][bcol + 4] = b1v;
        __syncthreads();
#pragma unroll
        for (int kk = 0; kk < 16; ++kk) {
            float4 a  = *(const float4*)&At[kk][ty * 4];
            float4 b0 = *(const float4*)&Bt[kk][tx * 8];
            float4 b1 = *(const float4*)&Bt[kk][tx * 8 + 4];
            float avv[4] = {a.x, a.y, a.z, a.w};
            float bvv[8] = {b0.x, b0.y, b0.z, b0.w, b1.x, b1.y, b1.z, b1.w};
#pragma unroll
            for (int i = 0; i < 4; ++i)
#pragma unroll
                for (int j = 0; j < 8; ++j)
                    acc[i][j] = fmaf(avv[i], bvv[j], acc[i][j]);
        }
        __syncthreads();
    }

    const float inv3 = 1.f / 3.f;
    float bm[8];
#pragma unroll
    for (int j = 0; j < 8; ++j) {
        int col = tx * 8 + j;
        bm[j] = (bias[col] + bias[HIDF + col] + bias[2 * HIDF + col]) * inv3;
    }
#pragma unroll
    for (int i = 0; i < 4; ++i) {
        int row = block_row + ty * 4 + i;
        if (row >= NNODES) continue;
        float v[8];
#pragma unroll
        for (int j = 0; j < 8; ++j) {
            float t = acc[i][j] * inv3 + bm[j];
            if (act) t = (t > 0.f) ? t : NEG_SLOPE * t;
            v[j] = t;
        }
        uint4 pk;
        pk.x = bf_pack(v[0], v[1]);
        pk.y = bf_pack(v[2], v[3]);
        pk.z = bf_pack(v[4], v[5]);
        pk.w = bf_pack(v[6], v[7]);
        *(uint4*)(hout + (size_t)row * (HIDF / 2) + tx * 4) = pk;
    }
}

// ---------------------------------------------------------------------------
// 6) Final linear: out[N,64] = h(bf16) @ Wout + bout
// ---------------------------------------------------------------------------
__global__ __launch_bounds__(256) void k_final(const uint* __restrict__ h,
                                               const float* __restrict__ Wout,
                                               const float* __restrict__ bout,
                                               float* __restrict__ out) {
    int tid = threadIdx.x;
    int col = tid & 63;
    int row = blockIdx.x * 4 + (tid >> 6);
    if (row >= NNODES) return;
    const uint* hp = h + (size_t)row * (HIDF / 2);
    float acc = bout[col];
#pragma unroll 8
    for (int ku = 0; ku < HIDF / 2; ++ku) {
        uint v = hp[ku];
        acc = fmaf(bf_lo(v), Wout[(2 * ku) * OUTF + col], acc);
        acc = fmaf(bf_hi(v), Wout[(2 * ku + 1) * OUTF + col], acc);
    }
    out[(size_t)row * OUTF + col] = acc;
}

// ---------------------------------------------------------------------------
// Host launcher
// ---------------------------------------------------------------------------
extern "C" void kernel_launch(void* const* d_in, const int* in_sizes, int n_in,
                              void* d_out, int out_size, void* d_ws, size_t ws_size,
                              hipStream_t stream) {
    const float* x    = (const float*)d_in[0];
    const int*   esrc = (const int*)d_in[1];
    const int*   edst = (const int*)d_in[2];
    const float* W0   = (const float*)d_in[3];
    const float* b0   = (const float*)d_in[4];
    const float* Wl   = (const float*)d_in[5];
    const float* bl   = (const float*)d_in[6];
    const float* Wout = (const float*)d_in[7];
    const float* bout = (const float*)d_in[8];
    float* out = (float*)d_out;

    char* ws = (char*)d_ws;
    size_t off = 0;
    auto carve = [&](size_t bytes) {
        size_t p = off;
        off += (bytes + 255) & ~(size_t)255;
        return p;
    };
    const size_t SZ_RN_I = (size_t)NR * NNODES * 4;
    // deg_out, deg_in, cursor contiguous -> single memset
    size_t o_deg_out = carve(SZ_RN_I);
    size_t o_deg_in  = carve(SZ_RN_I);
    size_t o_cursor  = carve(SZ_RN_I);
    size_t zero_span = off;
    size_t o_out_nrm = carve(SZ_RN_I);
    size_t o_in_nrm  = carve(SZ_RN_I);
    size_t o_row_ptr = carve((size_t)NR * (NNODES + 1) * 4);
    size_t o_csums   = carve((size_t)NR * NCHUNK * 4);
    size_t o_coffs   = carve((size_t)NR * NCHUNK * 4);
    size_t o_csr     = carve((size_t)NR * NE * 4);
    size_t o_agg     = carve((size_t)NR * NNODES * HIDF * 4);
    size_t o_xb      = carve((size_t)NNODES * (HIDF / 2) * 4);  // bf16 packed
    size_t o_h       = carve((size_t)NNODES * (HIDF / 2) * 4);  // bf16 packed
    (void)ws_size;

    int*   deg_out  = (int*)(ws + o_deg_out);
    int*   deg_in   = (int*)(ws + o_deg_in);
    int*   cursor   = (int*)(ws + o_cursor);
    float* out_norm = (float*)(ws + o_out_nrm);
    float* in_norm  = (float*)(ws + o_in_nrm);
    int*   row_ptr  = (int*)(ws + o_row_ptr);
    int*   csums    = (int*)(ws + o_csums);
    int*   coffs    = (int*)(ws + o_coffs);
    int*   csr_src  = (int*)(ws + o_csr);
    float* agg      = (float*)(ws + o_agg);
    uint*  xb       = (uint*)(ws + o_xb);
    uint*  h        = (uint*)(ws + o_h);

    hipMemsetAsync(ws, 0, zero_span, stream);

    int nEdgeBlocks = (NR * NE + 255) / 256;
    k_cast_x<<<(NNODES * (HIDF / 2) + 255) / 256, 256, 0, stream>>>(x, xb);
    k_degrees<<<nEdgeBlocks, 256, 0, stream>>>(esrc, edst, deg_out, deg_in);
    k_norms<<<(NR * NNODES + 255) / 256, 256, 0, stream>>>(deg_out, deg_in, out_norm, in_norm);
    k_scan1<<<NR * NCHUNK, SCAN_T, 0, stream>>>(deg_in, row_ptr, csums);
    k_scan2<<<1, 64, 0, stream>>>(csums, coffs);
    k_scan3<<<NR * NCHUNK, SCAN_T, 0, stream>>>(row_ptr, coffs);
    k_fill_csr<<<nEdgeBlocks, 256, 0, stream>>>(esrc, edst, row_ptr, cursor, csr_src);

    const int aggBlocks = (NR * NNODES + 3) / 4;
    const int mmBlocks  = (NNODES + 63) / 64;

    const uint* hin = xb;
    for (int l = 0; l < 5; ++l) {
        k_aggregate<<<aggBlocks, 256, 0, stream>>>(hin, out_norm, in_norm, row_ptr, csr_src, agg);
        const float* Wp = (l == 0) ? W0 : Wl + (size_t)(l - 1) * NR * HIDF * HIDF;
        const float* bp = (l == 0) ? b0 : bl + (size_t)(l - 1) * NR * HIDF;
        k_conv_mm<<<mmBlocks, 256, 0, stream>>>(agg, Wp, bp, h, (l < 4) ? 1 : 0);
        hin = h;
    }
    k_final<<<(NNODES + 3) / 4, 256, 0, stream>>>(h, Wout, bout, out);
}